// Round 8
// baseline (549.746 us; speedup 1.0000x reference)
//
#include <hip/hip_runtime.h>
#include <hip/hip_bf16.h>
#include <stdint.h>

#define N_NODES 8192
#define IN_F 512
#define OUT_F 256
#define KSPLIT 4

typedef __attribute__((ext_vector_type(8))) short bf16x8;
typedef __attribute__((ext_vector_type(4))) float f32x4;

__device__ __forceinline__ unsigned short f2bf_rn(float f) {
  union { float f; unsigned u; } v; v.f = f;
  unsigned r = v.u + 0x7FFFu + ((v.u >> 16) & 1u);
  return (unsigned short)(r >> 16);
}
__device__ __forceinline__ float bf2f(unsigned short h) {
  union { unsigned u; float f; } v; v.u = ((unsigned)h) << 16;
  return v.f;
}

__device__ __forceinline__ void gload_lds16(const void* g, void* l) {
  __builtin_amdgcn_global_load_lds(
      (const __attribute__((address_space(1))) unsigned int*)g,
      (__attribute__((address_space(3))) unsigned int*)l, 16, 0, 0);
}

// expand 8 mask bits -> 8 bf16 (0.0/1.0)
__device__ __forceinline__ bf16x8 expand_byte(unsigned m) {
  union { uint4 u; bf16x8 v; } r;
  r.u.x = ((m & 1u) | ((m & 2u) << 15)) * 0x3F80u;
  r.u.y = (((m >> 2) & 1u) | (((m >> 3) & 1u) << 16)) * 0x3F80u;
  r.u.z = (((m >> 4) & 1u) | (((m >> 5) & 1u) << 16)) * 0x3F80u;
  r.u.w = (((m >> 6) & 1u) | (((m >> 7) & 1u) << 16)) * 0x3F80u;
  return r.v;
}

// ---------------------------------------------------------------------------
// K0: W [512][256] f32 -> Wt_h/Wt_l [256][512] bf16 (transposed, hi/lo split)
// ---------------------------------------------------------------------------
__global__ __launch_bounds__(256) void k0_prep_w(const float* __restrict__ W,
                                                 short* __restrict__ Wh,
                                                 short* __restrict__ Wl) {
  int k = blockIdx.x;
  int c = threadIdx.x;
  float v = W[(size_t)k * OUT_F + c];
  unsigned short h = f2bf_rn(v);
  unsigned short l = f2bf_rn(v - bf2f(h));
  Wh[(size_t)c * IN_F + k] = (short)h;
  Wl[(size_t)c * IN_F + k] = (short)l;
}

// ---------------------------------------------------------------------------
// K1: H = X @ W + bias  (known-correct)
// ---------------------------------------------------------------------------
__global__ __launch_bounds__(256) void k1_gemm_h(
    const float* __restrict__ X, const short* __restrict__ Wh,
    const short* __restrict__ Wl, const float* __restrict__ bias,
    float* __restrict__ H) {
  __shared__ __align__(16) short Xh[64 * 64], Xl[64 * 64];
  __shared__ __align__(16) short Wsh[128 * 64], Wsl[128 * 64];
  const int tid = threadIdx.x;
  const int rb = blockIdx.x >> 1, cb = blockIdx.x & 1;
  const int r0 = rb * 64, c0 = cb * 128;
  const int lane = tid & 63, wid = tid >> 6;

  f32x4 acc[8];
#pragma unroll
  for (int i = 0; i < 8; ++i) acc[i] = (f32x4){0.f, 0.f, 0.f, 0.f};

  const int sr = tid >> 2;
  const int sk = (tid & 3) * 16;

  for (int kc = 0; kc < IN_F; kc += 64) {
    const float* xp = X + (size_t)(r0 + sr) * IN_F + kc + sk;
#pragma unroll
    for (int q = 0; q < 2; ++q) {
      f32x4 v0 = *(const f32x4*)(xp + q * 8);
      f32x4 v1 = *(const f32x4*)(xp + q * 8 + 4);
      bf16x8 hv, lv;
#pragma unroll
      for (int j = 0; j < 4; ++j) {
        unsigned short h0 = f2bf_rn(v0[j]);
        hv[j] = (short)h0; lv[j] = (short)f2bf_rn(v0[j] - bf2f(h0));
        unsigned short h1 = f2bf_rn(v1[j]);
        hv[4 + j] = (short)h1; lv[4 + j] = (short)f2bf_rn(v1[j] - bf2f(h1));
      }
      int kb = (sk >> 3) + q;
      int off = sr * 64 + ((kb ^ (sr & 7)) << 3);
      *(bf16x8*)(Xh + off) = hv;
      *(bf16x8*)(Xl + off) = lv;
    }
#pragma unroll
    for (int it = 0; it < 4; ++it) {
      int u = it * 256 + tid;
      int col = u >> 3, kb = u & 7;
      size_t goff = (size_t)(c0 + col) * IN_F + kc + kb * 8;
      int off = col * 64 + ((kb ^ (col & 7)) << 3);
      *(bf16x8*)(Wsh + off) = *(const bf16x8*)(Wh + goff);
      *(bf16x8*)(Wsl + off) = *(const bf16x8*)(Wl + goff);
    }
    __syncthreads();
    const int arow = wid * 16 + (lane & 15);
    const int khalf = lane >> 4;
#pragma unroll
    for (int ks = 0; ks < 2; ++ks) {
      int kb = ks * 4 + khalf;
      int aoff = arow * 64 + ((kb ^ (arow & 7)) << 3);
      bf16x8 ah = *(const bf16x8*)(Xh + aoff);
      bf16x8 al = *(const bf16x8*)(Xl + aoff);
#pragma unroll
      for (int n = 0; n < 8; ++n) {
        int col = n * 16 + (lane & 15);
        int boff = col * 64 + ((kb ^ (col & 7)) << 3);
        bf16x8 bh = *(const bf16x8*)(Wsh + boff);
        bf16x8 bl = *(const bf16x8*)(Wsl + boff);
        acc[n] = __builtin_amdgcn_mfma_f32_16x16x32_bf16(ah, bh, acc[n], 0, 0, 0);
        acc[n] = __builtin_amdgcn_mfma_f32_16x16x32_bf16(ah, bl, acc[n], 0, 0, 0);
        acc[n] = __builtin_amdgcn_mfma_f32_16x16x32_bf16(al, bh, acc[n], 0, 0, 0);
      }
    }
    __syncthreads();
  }
  const int orow = r0 + wid * 16 + ((lane >> 4) << 2);
#pragma unroll
  for (int n = 0; n < 8; ++n) {
    int col = c0 + n * 16 + (lane & 15);
    float b = bias[col];
#pragma unroll
    for (int r = 0; r < 4; ++r)
      H[(size_t)(orow + r) * OUT_F + col] = acc[n][r] + b;
  }
}

// ---------------------------------------------------------------------------
// K2: s_dst[j] = H[j,:] . phi[256:512]; also per-block max -> blockmax[2048]
// ---------------------------------------------------------------------------
__global__ __launch_bounds__(256) void k2_sdst(const float* __restrict__ H,
                                               const float* __restrict__ phi,
                                               float* __restrict__ sdst,
                                               float* __restrict__ blockmax) {
  __shared__ float r4[4];
  const int tid = threadIdx.x, lane = tid & 63, wid = tid >> 6;
  const int row = blockIdx.x * 4 + wid;
  f32x4 hv = *(const f32x4*)(H + (size_t)row * OUT_F + lane * 4);
  f32x4 pv = *(const f32x4*)(phi + OUT_F + lane * 4);
  float s = hv[0] * pv[0] + hv[1] * pv[1] + hv[2] * pv[2] + hv[3] * pv[3];
#pragma unroll
  for (int off = 32; off; off >>= 1) s += __shfl_xor(s, off);
  if (lane == 0) { sdst[row] = s; r4[wid] = s; }
  __syncthreads();
  if (tid == 0)
    blockmax[blockIdx.x] = fmaxf(fmaxf(r4[0], r4[1]), fmaxf(r4[2], r4[3]));
}

// ---------------------------------------------------------------------------
// K4: gmax = max(blockmax); e = exp(sdst-gmax);
//     Bs = (e ⊙ H)^T hi/lo bf16, PRE-SWIZZLED in global so k5's linear
//     global_load_lds lands XOR-swizzled in LDS.
// ---------------------------------------------------------------------------
__global__ __launch_bounds__(256) void k4_build(const float* __restrict__ H,
                                                const float* __restrict__ sdst,
                                                const float* __restrict__ blockmax,
                                                short* __restrict__ Bs,
                                                float* __restrict__ e) {
  __shared__ float t[64][65];
  __shared__ float red[4];
  const int tid = threadIdx.x;
  float m = -1e30f;
  for (int i = tid; i < 2048; i += 256) m = fmaxf(m, blockmax[i]);
#pragma unroll
  for (int off = 32; off; off >>= 1) m = fmaxf(m, __shfl_xor(m, off));
  if ((tid & 63) == 0) red[tid >> 6] = m;
  __syncthreads();
  const float gmax = fmaxf(fmaxf(red[0], red[1]), fmaxf(red[2], red[3]));

  const int tx = tid & 63, ty = tid >> 6;
  const int j0 = (blockIdx.x >> 2) * 64;
  const int c0 = (blockIdx.x & 3) * 64;
#pragma unroll
  for (int i = 0; i < 16; ++i)
    t[ty + i * 4][tx] = H[(size_t)(j0 + ty + i * 4) * OUT_F + c0 + tx];
  __syncthreads();
  const float ej = expf(sdst[j0 + tx] - gmax);
#pragma unroll
  for (int i = 0; i < 16; ++i) {
    int c = c0 + ty + i * 4;
    float v = ej * t[tx][ty + i * 4];
    unsigned short h = f2bf_rn(v);
    unsigned short l = f2bf_rn(v - bf2f(h));
    size_t kidx = (size_t)j0 + (tx ^ ((c & 7) << 3));
    Bs[(size_t)c * N_NODES + kidx] = (short)h;
    Bs[(size_t)(256 + c) * N_NODES + kidx] = (short)l;
  }
  if (c0 == 0 && tid < 64) e[j0 + tid] = expf(sdst[j0 + tid] - gmax);
}

// ---------------------------------------------------------------------------
// K3: prepass. Streams adj ONCE (268 MB, HBM-bound, fully resident):
//     bitsT[w][row] = 64-bit mask of cols [w*64,w*64+64) of (adj | I),
//     denom[row]    = sum_j (adj|I)[row][j] * e[j]   (free under the stream)
// ---------------------------------------------------------------------------
__global__ __launch_bounds__(512) void k3_bits(const int* __restrict__ adj,
                                               const float* __restrict__ e,
                                               unsigned long long* __restrict__ bitsT,
                                               float* __restrict__ denom) {
  const int tid = threadIdx.x, lane = tid & 63, wid = tid >> 6;
  const int row = blockIdx.x * 8 + wid;
  const int* ap = adj + (size_t)row * N_NODES;
  float ds = 0.f;
#pragma unroll 2
  for (int w = 0; w < 128; ++w) {
    int col = w * 64 + lane;
    int v = ap[col];
    bool m = (v != 0) || (col == row);
    unsigned long long word = __ballot(m);
    ds += m ? e[col] : 0.f;
    if (lane == 0) bitsT[(size_t)w * N_NODES + row] = word;
  }
#pragma unroll
  for (int off = 32; off; off >>= 1) ds += __shfl_xor(ds, off);
  if (lane == 0) denom[row] = ds;
}

// ---------------------------------------------------------------------------
// K5: part[ksi] = mask @ (e⊙H) via MFMA. A = 1-bit mask (expanded in-reg).
// BM=128, BN=128, BK=64; 256 thr = 4 waves (2x2), LDS 66 KB -> 2 blocks/CU.
// Grid 512 = rb(64) x [cb(2) x ksplit(4)]; orig&7 = XCD -> each XCD owns one
// (cb,ksi) 1 MB B-chunk + 2 MB bits chunk, L2-resident. Single-barrier
// prefetch pipeline, A+B both via global_load_lds.
// ---------------------------------------------------------------------------
__global__ __launch_bounds__(256) void k5_main(
    const unsigned long long* __restrict__ bitsT,
    const short* __restrict__ Bs,
    float* __restrict__ part, int kchunk) {
  __shared__ __align__(16) unsigned long long Abits[2][128];  // 2 KB
  __shared__ __align__(16) short Bb[2][2 * 128 * 64];         // 64 KB

  const int tid = threadIdx.x;
  const int orig = (int)blockIdx.x;
  const int rb = orig >> 3;
  const int x = orig & 7;            // XCD id (round-robin dispatch)
  const int cb = x & 1, ksi = x >> 1;
  const int r0 = rb * 128, c0 = cb * 128;
  const int w0 = ksi * 32;
  const long kbeg = (long)ksi * kchunk;
  const int lane = tid & 63, wid = tid >> 6;
  const int wr = wid >> 1, wc = wid & 1;

  f32x4 acc[4][4];
#pragma unroll
  for (int mi = 0; mi < 4; ++mi)
#pragma unroll
    for (int ni = 0; ni < 4; ++ni) acc[mi][ni] = (f32x4){0.f, 0.f, 0.f, 0.f};

  auto stage = [&](int t, int buf) {
    if (wid == 0)
      gload_lds16(bitsT + (size_t)(w0 + t) * N_NODES + r0 + lane * 2,
                  &Abits[buf][lane * 2]);
    const long kc = kbeg + (long)t * 64;
    const int p = wid >> 1, cg = wid & 1;
    const short* base = Bs + (size_t)p * 256 * N_NODES + kc;
#pragma unroll
    for (int i = 0; i < 8; ++i) {
      int col = c0 + cg * 64 + i * 8 + (lane >> 3);
      const short* g = base + (size_t)col * N_NODES + (lane & 7) * 8;
      short* l = &Bb[buf][(p * 128 + cg * 64 + i * 8) * 64];
      gload_lds16(g, l);
    }
  };

  auto compute = [&](int buf) {
    uint2 aw[4];
#pragma unroll
    for (int mi = 0; mi < 4; ++mi) {
      int row = wr * 64 + mi * 16 + (lane & 15);
      aw[mi] = *(const uint2*)&Abits[buf][row];
    }
    const int bsh = (lane >> 4) * 8;
#pragma unroll
    for (int ks = 0; ks < 2; ++ks) {
      const int kb = ks * 4 + (lane >> 4);
      bf16x8 af[4];
#pragma unroll
      for (int mi = 0; mi < 4; ++mi) {
        unsigned m = ((ks ? aw[mi].y : aw[mi].x) >> bsh) & 0xFFu;
        af[mi] = expand_byte(m);
      }
#pragma unroll
      for (int ni = 0; ni < 4; ++ni) {
        int colL = wc * 64 + ni * 16 + (lane & 15);
        int so = (kb ^ (colL & 7)) << 3;
        bf16x8 bh = *(const bf16x8*)&Bb[buf][colL * 64 + so];
        bf16x8 bl = *(const bf16x8*)&Bb[buf][(128 + colL) * 64 + so];
#pragma unroll
        for (int mi = 0; mi < 4; ++mi) {
          acc[mi][ni] = __builtin_amdgcn_mfma_f32_16x16x32_bf16(af[mi], bh, acc[mi][ni], 0, 0, 0);
          acc[mi][ni] = __builtin_amdgcn_mfma_f32_16x16x32_bf16(af[mi], bl, acc[mi][ni], 0, 0, 0);
        }
      }
    }
  };

  stage(0, 0);
  __syncthreads();
  const int NT = kchunk >> 6;
  for (int t = 0; t < NT; ++t) {
    const int cur = t & 1;
    if (t + 1 < NT) stage(t + 1, cur ^ 1);
    compute(cur);
    __syncthreads();
  }

  float* pbase = part + (size_t)ksi * N_NODES * OUT_F;
  const int orow0 = r0 + wr * 64 + ((lane >> 4) << 2);
#pragma unroll
  for (int mi = 0; mi < 4; ++mi) {
    int orow = orow0 + mi * 16;
#pragma unroll
    for (int ni = 0; ni < 4; ++ni) {
      int col = c0 + wc * 64 + ni * 16 + (lane & 15);
#pragma unroll
      for (int r = 0; r < 4; ++r)
        pbase[(size_t)(orow + r) * OUT_F + col] = acc[mi][ni][r];
    }
  }
}

// ---------------------------------------------------------------------------
// K6: out[i,f] = sum_p part[p][i][f] / denom[i]   (diag already in bitmask)
// ---------------------------------------------------------------------------
__global__ __launch_bounds__(256) void k6_final(const float* __restrict__ part,
                                                const float* __restrict__ denom,
                                                float* __restrict__ out) {
  const int i = blockIdx.x, f = threadIdx.x;
  float num = 0.f;
#pragma unroll
  for (int p = 0; p < KSPLIT; ++p)
    num += part[((size_t)p * N_NODES + i) * OUT_F + f];
  out[(size_t)i * OUT_F + f] = num / denom[i];
}

// ---------------------------------------------------------------------------
// Workspace layout (<= ~56.1 MB, within the proven-safe R1 envelope):
//   [0, 32MB):       Part (k5 out)  OVERLAYS  {H, Wh, Wl, Sd, Bm} (dead
//                    after k4; k6 does not read H — diag folded into bits)
//   [32MB, ...):     E, Bs, Bits, Den
// ---------------------------------------------------------------------------
extern "C" void kernel_launch(void* const* d_in, const int* in_sizes, int n_in,
                              void* d_out, int out_size, void* d_ws, size_t ws_size,
                              hipStream_t stream) {
  const float* x    = (const float*)d_in[0];
  const int*   adj  = (const int*)d_in[1];
  const float* w    = (const float*)d_in[2];
  const float* bias = (const float*)d_in[3];
  const float* phi  = (const float*)d_in[4];
  float* out = (float*)d_out;
  char* ws = (char*)d_ws;

  // overlay region [0, 32MB)
  const size_t PART_BYTES = (size_t)KSPLIT * N_NODES * OUT_F * 4;  // 32 MB
  size_t off = 0;
  auto alloc = [&](size_t bytes) {
    size_t o = off; off += (bytes + 255) & ~(size_t)255; return o;
  };
  size_t oPart = alloc(PART_BYTES);       // 0
  // sub-layout inside the overlay (dead after k4):
  size_t oH  = 0;                                        // 8 MB
  size_t oWh = oH + (size_t)N_NODES * OUT_F * 4;         // 0.25 MB
  size_t oWl = oWh + (size_t)OUT_F * IN_F * 2;           // 0.25 MB
  size_t oSd = oWl + (size_t)OUT_F * IN_F * 2;           // 32 KB
  size_t oBm = oSd + (size_t)N_NODES * 4;                // 8 KB
  // persistent region after the overlay:
  size_t oE   = alloc((size_t)N_NODES * 4);
  size_t oBs  = alloc((size_t)2 * OUT_F * N_NODES * 2);  // 16 MB
  size_t oBit = alloc((size_t)128 * N_NODES * 8);        // 8 MB
  size_t oDen = alloc((size_t)N_NODES * 4);
  (void)ws_size;

  float* H   = (float*)(ws + oH);
  short* Wh  = (short*)(ws + oWh);
  short* Wl  = (short*)(ws + oWl);
  float* Sd  = (float*)(ws + oSd);
  float* Bm  = (float*)(ws + oBm);
  float* E   = (float*)(ws + oE);
  short* Bs  = (short*)(ws + oBs);
  unsigned long long* Bits = (unsigned long long*)(ws + oBit);
  float* Den = (float*)(ws + oDen);
  float* Part = (float*)(ws + oPart);

  k0_prep_w<<<IN_F, OUT_F, 0, stream>>>(w, Wh, Wl);
  k1_gemm_h<<<256, 256, 0, stream>>>(x, Wh, Wl, bias, H);
  k2_sdst<<<N_NODES / 4, 256, 0, stream>>>(H, phi, Sd, Bm);
  k4_build<<<512, 256, 0, stream>>>(H, Sd, Bm, Bs, E);
  k3_bits<<<N_NODES / 8, 512, 0, stream>>>(adj, E, Bits, Den);
  k5_main<<<512, 256, 0, stream>>>(Bits, Bs, Part, N_NODES / KSPLIT);
  k6_final<<<N_NODES, 256, 0, stream>>>(Part, Den, out);
}

// Round 9
// 503.692 us; speedup vs baseline: 1.0914x; 1.0914x over previous
//
#include <hip/hip_runtime.h>
#include <hip/hip_bf16.h>
#include <stdint.h>

#define N_NODES 8192
#define IN_F 512
#define OUT_F 256
#define KSPLIT 4

typedef __attribute__((ext_vector_type(8))) short bf16x8;
typedef __attribute__((ext_vector_type(4))) float f32x4;

__device__ __forceinline__ unsigned short f2bf_rn(float f) {
  union { float f; unsigned u; } v; v.f = f;
  unsigned r = v.u + 0x7FFFu + ((v.u >> 16) & 1u);
  return (unsigned short)(r >> 16);
}
__device__ __forceinline__ float bf2f(unsigned short h) {
  union { unsigned u; float f; } v; v.u = ((unsigned)h) << 16;
  return v.f;
}

__device__ __forceinline__ void gload_lds16(const void* g, void* l) {
  __builtin_amdgcn_global_load_lds(
      (const __attribute__((address_space(1))) unsigned int*)g,
      (__attribute__((address_space(3))) unsigned int*)l, 16, 0, 0);
}

// expand 8 mask bits -> 8 bf16 (0.0/1.0)
__device__ __forceinline__ bf16x8 expand_byte(unsigned m) {
  union { uint4 u; bf16x8 v; } r;
  r.u.x = ((m & 1u) | ((m & 2u) << 15)) * 0x3F80u;
  r.u.y = (((m >> 2) & 1u) | (((m >> 3) & 1u) << 16)) * 0x3F80u;
  r.u.z = (((m >> 4) & 1u) | (((m >> 5) & 1u) << 16)) * 0x3F80u;
  r.u.w = (((m >> 6) & 1u) | (((m >> 7) & 1u) << 16)) * 0x3F80u;
  return r.v;
}

// ---------------------------------------------------------------------------
// K0: W [512][256] f32 -> Wt_h/Wt_l [256][512] bf16 (transposed, hi/lo split)
// ---------------------------------------------------------------------------
__global__ __launch_bounds__(256) void k0_prep_w(const float* __restrict__ W,
                                                 short* __restrict__ Wh,
                                                 short* __restrict__ Wl) {
  int k = blockIdx.x;
  int c = threadIdx.x;
  float v = W[(size_t)k * OUT_F + c];
  unsigned short h = f2bf_rn(v);
  unsigned short l = f2bf_rn(v - bf2f(h));
  Wh[(size_t)c * IN_F + k] = (short)h;
  Wl[(size_t)c * IN_F + k] = (short)l;
}

// ---------------------------------------------------------------------------
// K1: H = X @ W + bias  (known-correct)
// ---------------------------------------------------------------------------
__global__ __launch_bounds__(256) void k1_gemm_h(
    const float* __restrict__ X, const short* __restrict__ Wh,
    const short* __restrict__ Wl, const float* __restrict__ bias,
    float* __restrict__ H) {
  __shared__ __align__(16) short Xh[64 * 64], Xl[64 * 64];
  __shared__ __align__(16) short Wsh[128 * 64], Wsl[128 * 64];
  const int tid = threadIdx.x;
  const int rb = blockIdx.x >> 1, cb = blockIdx.x & 1;
  const int r0 = rb * 64, c0 = cb * 128;
  const int lane = tid & 63, wid = tid >> 6;

  f32x4 acc[8];
#pragma unroll
  for (int i = 0; i < 8; ++i) acc[i] = (f32x4){0.f, 0.f, 0.f, 0.f};

  const int sr = tid >> 2;
  const int sk = (tid & 3) * 16;

  for (int kc = 0; kc < IN_F; kc += 64) {
    const float* xp = X + (size_t)(r0 + sr) * IN_F + kc + sk;
#pragma unroll
    for (int q = 0; q < 2; ++q) {
      f32x4 v0 = *(const f32x4*)(xp + q * 8);
      f32x4 v1 = *(const f32x4*)(xp + q * 8 + 4);
      bf16x8 hv, lv;
#pragma unroll
      for (int j = 0; j < 4; ++j) {
        unsigned short h0 = f2bf_rn(v0[j]);
        hv[j] = (short)h0; lv[j] = (short)f2bf_rn(v0[j] - bf2f(h0));
        unsigned short h1 = f2bf_rn(v1[j]);
        hv[4 + j] = (short)h1; lv[4 + j] = (short)f2bf_rn(v1[j] - bf2f(h1));
      }
      int kb = (sk >> 3) + q;
      int off = sr * 64 + ((kb ^ (sr & 7)) << 3);
      *(bf16x8*)(Xh + off) = hv;
      *(bf16x8*)(Xl + off) = lv;
    }
#pragma unroll
    for (int it = 0; it < 4; ++it) {
      int u = it * 256 + tid;
      int col = u >> 3, kb = u & 7;
      size_t goff = (size_t)(c0 + col) * IN_F + kc + kb * 8;
      int off = col * 64 + ((kb ^ (col & 7)) << 3);
      *(bf16x8*)(Wsh + off) = *(const bf16x8*)(Wh + goff);
      *(bf16x8*)(Wsl + off) = *(const bf16x8*)(Wl + goff);
    }
    __syncthreads();
    const int arow = wid * 16 + (lane & 15);
    const int khalf = lane >> 4;
#pragma unroll
    for (int ks = 0; ks < 2; ++ks) {
      int kb = ks * 4 + khalf;
      int aoff = arow * 64 + ((kb ^ (arow & 7)) << 3);
      bf16x8 ah = *(const bf16x8*)(Xh + aoff);
      bf16x8 al = *(const bf16x8*)(Xl + aoff);
#pragma unroll
      for (int n = 0; n < 8; ++n) {
        int col = n * 16 + (lane & 15);
        int boff = col * 64 + ((kb ^ (col & 7)) << 3);
        bf16x8 bh = *(const bf16x8*)(Wsh + boff);
        bf16x8 bl = *(const bf16x8*)(Wsl + boff);
        acc[n] = __builtin_amdgcn_mfma_f32_16x16x32_bf16(ah, bh, acc[n], 0, 0, 0);
        acc[n] = __builtin_amdgcn_mfma_f32_16x16x32_bf16(ah, bl, acc[n], 0, 0, 0);
        acc[n] = __builtin_amdgcn_mfma_f32_16x16x32_bf16(al, bh, acc[n], 0, 0, 0);
      }
    }
    __syncthreads();
  }
  const int orow = r0 + wid * 16 + ((lane >> 4) << 2);
#pragma unroll
  for (int n = 0; n < 8; ++n) {
    int col = c0 + n * 16 + (lane & 15);
    float b = bias[col];
#pragma unroll
    for (int r = 0; r < 4; ++r)
      H[(size_t)(orow + r) * OUT_F + col] = acc[n][r] + b;
  }
}

// ---------------------------------------------------------------------------
// K2: s_dst[j] = H[j,:] . phi[256:512]; also per-block max -> blockmax[2048]
// ---------------------------------------------------------------------------
__global__ __launch_bounds__(256) void k2_sdst(const float* __restrict__ H,
                                               const float* __restrict__ phi,
                                               float* __restrict__ sdst,
                                               float* __restrict__ blockmax) {
  __shared__ float r4[4];
  const int tid = threadIdx.x, lane = tid & 63, wid = tid >> 6;
  const int row = blockIdx.x * 4 + wid;
  f32x4 hv = *(const f32x4*)(H + (size_t)row * OUT_F + lane * 4);
  f32x4 pv = *(const f32x4*)(phi + OUT_F + lane * 4);
  float s = hv[0] * pv[0] + hv[1] * pv[1] + hv[2] * pv[2] + hv[3] * pv[3];
#pragma unroll
  for (int off = 32; off; off >>= 1) s += __shfl_xor(s, off);
  if (lane == 0) { sdst[row] = s; r4[wid] = s; }
  __syncthreads();
  if (tid == 0)
    blockmax[blockIdx.x] = fmaxf(fmaxf(r4[0], r4[1]), fmaxf(r4[2], r4[3]));
}

// ---------------------------------------------------------------------------
// K4: gmax = max(blockmax); e = exp(sdst-gmax);
//     Bs = (e ⊙ H)^T hi/lo bf16, PRE-SWIZZLED in global so k5's linear
//     global_load_lds lands XOR-swizzled in LDS.
// ---------------------------------------------------------------------------
__global__ __launch_bounds__(256) void k4_build(const float* __restrict__ H,
                                                const float* __restrict__ sdst,
                                                const float* __restrict__ blockmax,
                                                short* __restrict__ Bs,
                                                float* __restrict__ e) {
  __shared__ float t[64][65];
  __shared__ float red[4];
  const int tid = threadIdx.x;
  float m = -1e30f;
  for (int i = tid; i < 2048; i += 256) m = fmaxf(m, blockmax[i]);
#pragma unroll
  for (int off = 32; off; off >>= 1) m = fmaxf(m, __shfl_xor(m, off));
  if ((tid & 63) == 0) red[tid >> 6] = m;
  __syncthreads();
  const float gmax = fmaxf(fmaxf(red[0], red[1]), fmaxf(red[2], red[3]));

  const int tx = tid & 63, ty = tid >> 6;
  const int j0 = (blockIdx.x >> 2) * 64;
  const int c0 = (blockIdx.x & 3) * 64;
#pragma unroll
  for (int i = 0; i < 16; ++i)
    t[ty + i * 4][tx] = H[(size_t)(j0 + ty + i * 4) * OUT_F + c0 + tx];
  __syncthreads();
  const float ej = expf(sdst[j0 + tx] - gmax);
#pragma unroll
  for (int i = 0; i < 16; ++i) {
    int c = c0 + ty + i * 4;
    float v = ej * t[tx][ty + i * 4];
    unsigned short h = f2bf_rn(v);
    unsigned short l = f2bf_rn(v - bf2f(h));
    size_t kidx = (size_t)j0 + (tx ^ ((c & 7) << 3));
    Bs[(size_t)c * N_NODES + kidx] = (short)h;
    Bs[(size_t)(256 + c) * N_NODES + kidx] = (short)l;
  }
  if (c0 == 0 && tid < 64) e[j0 + tid] = expf(sdst[j0 + tid] - gmax);
}

// ---------------------------------------------------------------------------
// K3: prepass, VECTORIZED (int4 adj + float4 e, 16B/lane).
// Per iter c: lane l covers cols c*256 + l*4 .. +3 (4 bits). The 64-bit word
// w = c*4 + (l>>4) is assembled by OR-reduce over the 16-lane group
// (bit (l&15)*4+j  <->  col w*64 + (l&15)*4+j — identical to ballot order,
// so k5's expand is unchanged). denom accumulated under the stream.
// ---------------------------------------------------------------------------
__global__ __launch_bounds__(512) void k3_bits(const int* __restrict__ adj,
                                               const float* __restrict__ e,
                                               unsigned long long* __restrict__ bitsT,
                                               float* __restrict__ denom) {
  const int tid = threadIdx.x, lane = tid & 63, wid = tid >> 6;
  const int row = blockIdx.x * 8 + wid;
  const int sub = lane & 15, grp = lane >> 4;
  const int* ap = adj + (size_t)row * N_NODES + lane * 4;
  const float* ep = e + lane * 4;
  float ds = 0.f;
#pragma unroll 4
  for (int c = 0; c < 32; ++c) {
    const int base = c * 256;
    int4 av = *(const int4*)(ap + base);
    f32x4 ev = *(const f32x4*)(ep + base);
    const int col0 = base + lane * 4;
    unsigned b = 0;
    if (av.x != 0 || col0 + 0 == row) { b |= 1u; ds += ev[0]; }
    if (av.y != 0 || col0 + 1 == row) { b |= 2u; ds += ev[1]; }
    if (av.z != 0 || col0 + 2 == row) { b |= 4u; ds += ev[2]; }
    if (av.w != 0 || col0 + 3 == row) { b |= 8u; ds += ev[3]; }
    unsigned long long local = (unsigned long long)b << (sub * 4);
    local |= __shfl_xor(local, 1);
    local |= __shfl_xor(local, 2);
    local |= __shfl_xor(local, 4);
    local |= __shfl_xor(local, 8);
    if (sub == 0) bitsT[(size_t)(c * 4 + grp) * N_NODES + row] = local;
  }
#pragma unroll
  for (int off = 32; off; off >>= 1) ds += __shfl_xor(ds, off);
  if (lane == 0) denom[row] = ds;
}

// ---------------------------------------------------------------------------
// K5: part[ksi] = mask @ (e⊙H) via MFMA. A = 1-bit mask (expanded in-reg).
// BM=128, BN=128, BK=64; 256 thr = 4 waves (2x2), LDS 66 KB -> 2 blocks/CU.
// Grid 512 = rb(64) x [cb(2) x ksplit(4)]; orig&7 = XCD -> each XCD owns one
// (cb,ksi) 1 MB B-chunk + 2 MB bits chunk, L2-resident. Single-barrier
// prefetch pipeline, A+B both via global_load_lds.
// ---------------------------------------------------------------------------
__global__ __launch_bounds__(256) void k5_main(
    const unsigned long long* __restrict__ bitsT,
    const short* __restrict__ Bs,
    float* __restrict__ part, int kchunk) {
  __shared__ __align__(16) unsigned long long Abits[2][128];  // 2 KB
  __shared__ __align__(16) short Bb[2][2 * 128 * 64];         // 64 KB

  const int tid = threadIdx.x;
  const int orig = (int)blockIdx.x;
  const int rb = orig >> 3;
  const int x = orig & 7;            // XCD id (round-robin dispatch)
  const int cb = x & 1, ksi = x >> 1;
  const int r0 = rb * 128, c0 = cb * 128;
  const int w0 = ksi * 32;
  const long kbeg = (long)ksi * kchunk;
  const int lane = tid & 63, wid = tid >> 6;
  const int wr = wid >> 1, wc = wid & 1;

  f32x4 acc[4][4];
#pragma unroll
  for (int mi = 0; mi < 4; ++mi)
#pragma unroll
    for (int ni = 0; ni < 4; ++ni) acc[mi][ni] = (f32x4){0.f, 0.f, 0.f, 0.f};

  auto stage = [&](int t, int buf) {
    if (wid == 0)
      gload_lds16(bitsT + (size_t)(w0 + t) * N_NODES + r0 + lane * 2,
                  &Abits[buf][lane * 2]);
    const long kc = kbeg + (long)t * 64;
    const int p = wid >> 1, cg = wid & 1;
    const short* base = Bs + (size_t)p * 256 * N_NODES + kc;
#pragma unroll
    for (int i = 0; i < 8; ++i) {
      int col = c0 + cg * 64 + i * 8 + (lane >> 3);
      const short* g = base + (size_t)col * N_NODES + (lane & 7) * 8;
      short* l = &Bb[buf][(p * 128 + cg * 64 + i * 8) * 64];
      gload_lds16(g, l);
    }
  };

  auto compute = [&](int buf) {
    uint2 aw[4];
#pragma unroll
    for (int mi = 0; mi < 4; ++mi) {
      int row = wr * 64 + mi * 16 + (lane & 15);
      aw[mi] = *(const uint2*)&Abits[buf][row];
    }
    const int bsh = (lane >> 4) * 8;
#pragma unroll
    for (int ks = 0; ks < 2; ++ks) {
      const int kb = ks * 4 + (lane >> 4);
      bf16x8 af[4];
#pragma unroll
      for (int mi = 0; mi < 4; ++mi) {
        unsigned m = ((ks ? aw[mi].y : aw[mi].x) >> bsh) & 0xFFu;
        af[mi] = expand_byte(m);
      }
#pragma unroll
      for (int ni = 0; ni < 4; ++ni) {
        int colL = wc * 64 + ni * 16 + (lane & 15);
        int so = (kb ^ (colL & 7)) << 3;
        bf16x8 bh = *(const bf16x8*)&Bb[buf][colL * 64 + so];
        bf16x8 bl = *(const bf16x8*)&Bb[buf][(128 + colL) * 64 + so];
#pragma unroll
        for (int mi = 0; mi < 4; ++mi) {
          acc[mi][ni] = __builtin_amdgcn_mfma_f32_16x16x32_bf16(af[mi], bh, acc[mi][ni], 0, 0, 0);
          acc[mi][ni] = __builtin_amdgcn_mfma_f32_16x16x32_bf16(af[mi], bl, acc[mi][ni], 0, 0, 0);
        }
      }
    }
  };

  stage(0, 0);
  __syncthreads();
  const int NT = kchunk >> 6;
  for (int t = 0; t < NT; ++t) {
    const int cur = t & 1;
    if (t + 1 < NT) stage(t + 1, cur ^ 1);
    compute(cur);
    __syncthreads();
  }

  float* pbase = part + (size_t)ksi * N_NODES * OUT_F;
  const int orow0 = r0 + wr * 64 + ((lane >> 4) << 2);
#pragma unroll
  for (int mi = 0; mi < 4; ++mi) {
    int orow = orow0 + mi * 16;
#pragma unroll
    for (int ni = 0; ni < 4; ++ni) {
      int col = c0 + wc * 64 + ni * 16 + (lane & 15);
#pragma unroll
      for (int r = 0; r < 4; ++r)
        pbase[(size_t)(orow + r) * OUT_F + col] = acc[mi][ni][r];
    }
  }
}

// ---------------------------------------------------------------------------
// K6: out[i,f] = sum_p part[p][i][f] / denom[i]   (diag already in bitmask)
// ---------------------------------------------------------------------------
__global__ __launch_bounds__(256) void k6_final(const float* __restrict__ part,
                                                const float* __restrict__ denom,
                                                float* __restrict__ out) {
  const int i = blockIdx.x, f = threadIdx.x;
  float num = 0.f;
#pragma unroll
  for (int p = 0; p < KSPLIT; ++p)
    num += part[((size_t)p * N_NODES + i) * OUT_F + f];
  out[(size_t)i * OUT_F + f] = num / denom[i];
}

// ---------------------------------------------------------------------------
// Workspace layout (<= ~56.1 MB, within the proven-safe R1 envelope):
//   [0, 32MB):       Part (k5 out)  OVERLAYS  {H, Wh, Wl, Sd, Bm} (dead
//                    after k4; k6 does not read H — diag folded into bits)
//   [32MB, ...):     E, Bs, Bits, Den
// ---------------------------------------------------------------------------
extern "C" void kernel_launch(void* const* d_in, const int* in_sizes, int n_in,
                              void* d_out, int out_size, void* d_ws, size_t ws_size,
                              hipStream_t stream) {
  const float* x    = (const float*)d_in[0];
  const int*   adj  = (const int*)d_in[1];
  const float* w    = (const float*)d_in[2];
  const float* bias = (const float*)d_in[3];
  const float* phi  = (const float*)d_in[4];
  float* out = (float*)d_out;
  char* ws = (char*)d_ws;

  // overlay region [0, 32MB)
  const size_t PART_BYTES = (size_t)KSPLIT * N_NODES * OUT_F * 4;  // 32 MB
  size_t off = 0;
  auto alloc = [&](size_t bytes) {
    size_t o = off; off += (bytes + 255) & ~(size_t)255; return o;
  };
  size_t oPart = alloc(PART_BYTES);       // 0
  // sub-layout inside the overlay (dead after k4):
  size_t oH  = 0;                                        // 8 MB
  size_t oWh = oH + (size_t)N_NODES * OUT_F * 4;         // 0.25 MB
  size_t oWl = oWh + (size_t)OUT_F * IN_F * 2;           // 0.25 MB
  size_t oSd = oWl + (size_t)OUT_F * IN_F * 2;           // 32 KB
  size_t oBm = oSd + (size_t)N_NODES * 4;                // 8 KB
  // persistent region after the overlay:
  size_t oE   = alloc((size_t)N_NODES * 4);
  size_t oBs  = alloc((size_t)2 * OUT_F * N_NODES * 2);  // 16 MB
  size_t oBit = alloc((size_t)128 * N_NODES * 8);        // 8 MB
  size_t oDen = alloc((size_t)N_NODES * 4);
  (void)ws_size;

  float* H   = (float*)(ws + oH);
  short* Wh  = (short*)(ws + oWh);
  short* Wl  = (short*)(ws + oWl);
  float* Sd  = (float*)(ws + oSd);
  float* Bm  = (float*)(ws + oBm);
  float* E   = (float*)(ws + oE);
  short* Bs  = (short*)(ws + oBs);
  unsigned long long* Bits = (unsigned long long*)(ws + oBit);
  float* Den = (float*)(ws + oDen);
  float* Part = (float*)(ws + oPart);

  k0_prep_w<<<IN_F, OUT_F, 0, stream>>>(w, Wh, Wl);
  k1_gemm_h<<<256, 256, 0, stream>>>(x, Wh, Wl, bias, H);
  k2_sdst<<<N_NODES / 4, 256, 0, stream>>>(H, phi, Sd, Bm);
  k4_build<<<512, 256, 0, stream>>>(H, Sd, Bm, Bs, E);
  k3_bits<<<N_NODES / 8, 512, 0, stream>>>(adj, E, Bits, Den);
  k5_main<<<512, 256, 0, stream>>>(Bits, Bs, Part, N_NODES / KSPLIT);
  k6_final<<<N_NODES, 256, 0, stream>>>(Part, Den, out);
}